// Round 3
// baseline (8145.775 us; speedup 1.0000x reference)
//
#include <hip/hip_runtime.h>
#include <math.h>

#define NVV 100000
#define NCC 420000
#define EE  630000
#define HH  128
#define LL  8

typedef unsigned int uint;

// ---------------- bf16 helpers (bit-level, RNE) ----------------
__device__ inline float bf2f(uint u){ return __uint_as_float(u << 16); }
__device__ inline uint  f2bf(float f){
  uint b = __float_as_uint(f);
  return (b + 0x7FFFu + ((b >> 16) & 1u)) >> 16;
}
__device__ inline uint pack2(float a, float b){ return f2bf(a) | (f2bf(b) << 16); }
__device__ inline float4 relu4(float4 v){
  v.x = fmaxf(v.x, 0.f); v.y = fmaxf(v.y, 0.f);
  v.z = fmaxf(v.z, 0.f); v.w = fmaxf(v.w, 0.f);
  return v;
}

__global__ void k_sentinel(float* out, float v){
  if (blockIdx.x == 0 && threadIdx.x == 0) out[0] = v;
}

// ---------------- embeddings ----------------
__device__ inline float4 vemb4(const float* __restrict__ xv, const float* __restrict__ W,
                               const float* __restrict__ b, int i, int h4){
  float x0 = xv[4*i+0], x1 = xv[4*i+1], x2 = xv[4*i+2], x3 = xv[4*i+3];
  float4 w0 = *(const float4*)(W + 0*HH + h4);
  float4 w1 = *(const float4*)(W + 1*HH + h4);
  float4 w2 = *(const float4*)(W + 2*HH + h4);
  float4 w3 = *(const float4*)(W + 3*HH + h4);
  float4 bb = *(const float4*)(b + h4);
  float4 r;
  r.x = fmaf(x0,w0.x, fmaf(x1,w1.x, fmaf(x2,w2.x, fmaf(x3,w3.x, bb.x))));
  r.y = fmaf(x0,w0.y, fmaf(x1,w1.y, fmaf(x2,w2.y, fmaf(x3,w3.y, bb.y))));
  r.z = fmaf(x0,w0.z, fmaf(x1,w1.z, fmaf(x2,w2.z, fmaf(x3,w3.z, bb.z))));
  r.w = fmaf(x0,w0.w, fmaf(x1,w1.w, fmaf(x2,w2.w, fmaf(x3,w3.w, bb.w))));
  return r;
}

__global__ void k_embed_v(const float* __restrict__ xv, const float* __restrict__ W,
                          const float* __restrict__ b, float* __restrict__ out){
  int tid = blockIdx.x * 256 + threadIdx.x;
  int i = tid >> 5;
  if (i >= NVV) return;
  int h4 = (tid & 31) << 2;
  *(float4*)(out + (size_t)i*HH + h4) = relu4(vemb4(xv, W, b, i, h4));
}

__global__ void k_embed_c(const float* __restrict__ xc, const float* __restrict__ W,
                          const float* __restrict__ b, uint* __restrict__ out){
  int tid = blockIdx.x * 256 + threadIdx.x;
  int i = tid >> 5;
  if (i >= NCC) return;
  int c2 = tid & 31;
  int h4 = c2 << 2;
  float x0 = xc[i];
  float4 w = *(const float4*)(W + h4);
  float4 bb = *(const float4*)(b + h4);
  float4 r;
  r.x = fmaxf(fmaf(x0, w.x, bb.x), 0.f);
  r.y = fmaxf(fmaf(x0, w.y, bb.y), 0.f);
  r.z = fmaxf(fmaf(x0, w.z, bb.z), 0.f);
  r.w = fmaxf(fmaf(x0, w.w, bb.w), 0.f);
  uint2 o; o.x = pack2(r.x, r.y); o.y = pack2(r.z, r.w);
  *(uint2*)(out + (size_t)i*64 + c2*2) = o;
}

// ---------------- CSR build ----------------
__global__ void k_counti(const int* __restrict__ d, int* cnt, int n){
  int i = blockIdx.x * 256 + threadIdx.x;
  if (i < n) atomicAdd(&cnt[d[i]], 1);
}

#define SCAN256(ts, t) \
  for (int off = 1; off < 256; off <<= 1){ \
    int _a = (t >= off) ? ts[t - off] : 0; \
    __syncthreads(); \
    ts[t] += _a; \
    __syncthreads(); \
  }

__global__ void k_scanb(const int* __restrict__ in, int* __restrict__ out,
                        int* __restrict__ part, int n){
  __shared__ int ts[256];
  int b = blockIdx.x, t = threadIdx.x;
  int base = b*1024 + t*4;
  int v0 = (base+0 < n) ? in[base+0] : 0;
  int v1 = (base+1 < n) ? in[base+1] : 0;
  int v2 = (base+2 < n) ? in[base+2] : 0;
  int v3 = (base+3 < n) ? in[base+3] : 0;
  int s1 = v0, s2 = s1+v1, s3 = s2+v2, tsum = s3+v3;
  ts[t] = tsum; __syncthreads();
  SCAN256(ts, t)
  int excl = ts[t] - tsum;
  if (base+0 < n) out[base+0] = excl;
  if (base+1 < n) out[base+1] = excl + s1;
  if (base+2 < n) out[base+2] = excl + s2;
  if (base+3 < n) out[base+3] = excl + s3;
  if (t == 255) part[b] = ts[255];
}

__global__ void k_scanp(int* p, int nb){
  __shared__ int ts[256];
  __shared__ int carry;
  int t = threadIdx.x;
  if (t == 0) carry = 0;
  __syncthreads();
  for (int c = 0; c*256 < nb; ++c){
    int i = c*256 + t;
    int v = (i < nb) ? p[i] : 0;
    ts[t] = v; __syncthreads();
    SCAN256(ts, t)
    int excl = ts[t] - v + carry;
    if (i < nb) p[i] = excl;
    int tot = ts[255];
    __syncthreads();
    if (t == 0) carry += tot;
    __syncthreads();
  }
}

__global__ void k_scana(int* out, const int* __restrict__ part, int n){
  int i = blockIdx.x * 256 + threadIdx.x;
  if (i < n) out[i] += part[i >> 10];
}

// uses ip[] as cursors: post-fill, ip[i] = end of segment i; start = i? ip[i-1] : 0
__global__ void k_fill(const int* __restrict__ dst, const int* __restrict__ pay,
                       int* cur, int* __restrict__ eo, int n){
  int i = blockIdx.x * 256 + threadIdx.x;
  if (i >= n) return;
  int p = atomicAdd(&cur[dst[i]], 1);
  eo[p] = pay[i];
}

// ---------------- misc ----------------
__global__ void k_addmat(const float* __restrict__ a, const float* __restrict__ b,
                         float* __restrict__ o, int n4){
  int i = blockIdx.x * 256 + threadIdx.x;
  if (i >= n4) return;
  float4 va = ((const float4*)a)[i];
  float4 vb = ((const float4*)b)[i];
  va.x += vb.x; va.y += vb.y; va.z += vb.z; va.w += vb.w;
  ((float4*)o)[i] = va;
}

// ---------------- v-side CSR gather-mean (wave per variable row) ----------------
__global__ void k_vgather(const uint* __restrict__ ch,
                          const int* __restrict__ ipp, const int* __restrict__ epp,
                          const int* __restrict__ ipn, const int* __restrict__ epn,
                          uint* __restrict__ Up, uint* __restrict__ Un){
  int g = blockIdx.x * 256 + threadIdx.x;
  int v = g >> 6, lane = g & 63;
  if (v >= NVV) return;
  int s = v ? ipp[v-1] : 0, e = ipp[v];
  float a0 = 0.f, a1 = 0.f;
  for (int j = s; j < e; ++j){
    uint u = ch[(size_t)epp[j]*64 + lane];
    a0 += bf2f(u & 0xFFFFu); a1 += bf2f(u >> 16);
  }
  float inv = 1.f / fmaxf((float)(e - s), 1.f);
  Up[(size_t)v*64 + lane] = pack2(a0*inv, a1*inv);
  s = v ? ipn[v-1] : 0; e = ipn[v];
  a0 = 0.f; a1 = 0.f;
  for (int j = s; j < e; ++j){
    uint u = ch[(size_t)epn[j]*64 + lane];
    a0 += bf2f(u & 0xFFFFu); a1 += bf2f(u >> 16);
  }
  inv = 1.f / fmaxf((float)(e - s), 1.f);
  Un[(size_t)v*64 + lane] = pack2(a0*inv, a1*inv);
}

// ---------------- GEMM pieces (512 threads, 128x128 tile, 128 KiB LDS) ----------------
#define FMA4(ACC, BV) \
  ACC.x += a.x*BV[0].x + a.y*BV[1].x + a.z*BV[2].x + a.w*BV[3].x; \
  ACC.y += a.x*BV[0].y + a.y*BV[1].y + a.z*BV[2].y + a.w*BV[3].y; \
  ACC.z += a.x*BV[0].z + a.y*BV[1].z + a.z*BV[2].z + a.w*BV[3].z; \
  ACC.w += a.x*BV[0].w + a.y*BV[1].w + a.z*BV[2].w + a.w*BV[3].w;

__device__ inline void stageA_f32(const float* A, float4* As4, int m0, int M, int t){
  const float4* A4 = (const float4*)A;
  #pragma unroll
  for (int j = 0; j < 8; ++j){
    int idx = j*512 + t, row = idx >> 5, c4 = idx & 31;
    float4 av = make_float4(0.f,0.f,0.f,0.f);
    if (m0 + row < M) av = A4[(size_t)(m0 + row)*32 + c4];
    As4[row*32 + (c4 ^ ((row >> 3) & 15))] = av;
  }
}

__device__ inline void stageA_bf(const uint* A, float4* As4, int m0, int M, int t){
  const uint2* A2 = (const uint2*)A;
  #pragma unroll
  for (int j = 0; j < 8; ++j){
    int idx = j*512 + t, row = idx >> 5, c4 = idx & 31;
    float4 av = make_float4(0.f,0.f,0.f,0.f);
    if (m0 + row < M){
      uint2 u = A2[(size_t)(m0 + row)*32 + c4];
      av.x = bf2f(u.x & 0xFFFFu); av.y = bf2f(u.x >> 16);
      av.z = bf2f(u.y & 0xFFFFu); av.w = bf2f(u.y >> 16);
    }
    As4[row*32 + (c4 ^ ((row >> 3) & 15))] = av;
  }
}

__device__ inline void stageB(const float* B, float4* Bs4, int t){
  const float4* B4 = (const float4*)B;
  #pragma unroll
  for (int j = 0; j < 8; ++j) Bs4[j*512 + t] = B4[j*512 + t];
}

__device__ inline void kloop(const float4* As4, const float4* Bs4, int rg, int cg,
                             float4 acc0[4], float4 acc1[4]){
  for (int k = 0; k < 128; k += 4){
    float4 b0[4], b1[4];
    #pragma unroll
    for (int j = 0; j < 4; ++j){
      b0[j] = Bs4[(k+j)*32 + cg];
      b1[j] = Bs4[(k+j)*32 + cg + 16];
    }
    #pragma unroll
    for (int r = 0; r < 4; ++r){
      int lr = rg*4 + r;
      float4 a = As4[lr*32 + ((k >> 2) ^ ((lr >> 3) & 15))];
      FMA4(acc0[r], b0)
      FMA4(acc1[r], b1)
    }
  }
}

#define ZERO4(A) { A[0]=A[1]=A[2]=A[3]=make_float4(0.f,0.f,0.f,0.f); }

// y_p = A@Bp, y_n = A@Bn  (A f32, outputs bf16)
__global__ __launch_bounds__(512) void k_gemm_dual(const float* __restrict__ A,
    const float* __restrict__ Bp, const float* __restrict__ Bn,
    uint* __restrict__ Up, uint* __restrict__ Un, int M){
  __shared__ float4 As4[4096];
  __shared__ float4 Bs4[4096];
  int t = threadIdx.x, m0 = blockIdx.x * 128;
  stageA_f32(A, As4, m0, M, t);
  stageB(Bp, Bs4, t);
  __syncthreads();
  int cg = t & 15, rg = t >> 4;
  float4 p0[4], p1[4], n0[4], n1[4];
  ZERO4(p0) ZERO4(p1) ZERO4(n0) ZERO4(n1)
  kloop(As4, Bs4, rg, cg, p0, p1);
  __syncthreads();
  stageB(Bn, Bs4, t);
  __syncthreads();
  kloop(As4, Bs4, rg, cg, n0, n1);
  #pragma unroll
  for (int r = 0; r < 4; ++r){
    int row = m0 + rg*4 + r;
    if (row >= M) continue;
    uint2 u;
    u.x = pack2(p0[r].x, p0[r].y); u.y = pack2(p0[r].z, p0[r].w);
    *(uint2*)(Up + (size_t)row*64 + cg*2) = u;
    u.x = pack2(p1[r].x, p1[r].y); u.y = pack2(p1[r].z, p1[r].w);
    *(uint2*)(Up + (size_t)row*64 + 32 + cg*2) = u;
    u.x = pack2(n0[r].x, n0[r].y); u.y = pack2(n0[r].z, n0[r].w);
    *(uint2*)(Un + (size_t)row*64 + cg*2) = u;
    u.x = pack2(n1[r].x, n1[r].y); u.y = pack2(n1[r].z, n1[r].w);
    *(uint2*)(Un + (size_t)row*64 + 32 + cg*2) = u;
  }
}

// vmid = 0.9*(Ap@Bp + An@Bn + Af@Bf + blp + bln) + 0.1*relu(vemb)   (bf16 out)
__global__ __launch_bounds__(512) void k_gemm3(const uint* __restrict__ Ap, const float* __restrict__ Bp,
    const uint* __restrict__ An, const float* __restrict__ Bn,
    const float* __restrict__ Af, const float* __restrict__ Bf,
    const float* __restrict__ xv, const float* __restrict__ Wve, const float* __restrict__ bve,
    const float* __restrict__ blp, const float* __restrict__ bln,
    uint* __restrict__ vmid, int M){
  __shared__ float4 As4[4096];
  __shared__ float4 Bs4[4096];
  int t = threadIdx.x, m0 = blockIdx.x * 128;
  int cg = t & 15, rg = t >> 4;
  float4 acc0[4], acc1[4];
  ZERO4(acc0) ZERO4(acc1)

  stageA_bf(Ap, As4, m0, M, t); stageB(Bp, Bs4, t);
  __syncthreads();
  kloop(As4, Bs4, rg, cg, acc0, acc1);
  __syncthreads();
  stageA_bf(An, As4, m0, M, t); stageB(Bn, Bs4, t);
  __syncthreads();
  kloop(As4, Bs4, rg, cg, acc0, acc1);
  __syncthreads();
  stageA_f32(Af, As4, m0, M, t); stageB(Bf, Bs4, t);
  __syncthreads();
  kloop(As4, Bs4, rg, cg, acc0, acc1);

  const float4* Wv4 = (const float4*)Wve;
  float4 w0a = Wv4[0*32+cg], w1a = Wv4[1*32+cg], w2a = Wv4[2*32+cg], w3a = Wv4[3*32+cg];
  float4 w0b = Wv4[0*32+cg+16], w1b = Wv4[1*32+cg+16], w2b = Wv4[2*32+cg+16], w3b = Wv4[3*32+cg+16];
  float4 ba  = ((const float4*)bve)[cg],  bb  = ((const float4*)bve)[cg+16];
  float4 bpa = ((const float4*)blp)[cg],  bpb = ((const float4*)blp)[cg+16];
  float4 bna = ((const float4*)bln)[cg],  bnb = ((const float4*)bln)[cg+16];
  #pragma unroll
  for (int r = 0; r < 4; ++r){
    int row = m0 + rg*4 + r;
    if (row >= M) continue;
    float x0 = xv[4*row+0], x1 = xv[4*row+1], x2 = xv[4*row+2], x3 = xv[4*row+3];
    float4 h0, h1, o0, o1;
    h0.x = fmaf(x0,w0a.x, fmaf(x1,w1a.x, fmaf(x2,w2a.x, fmaf(x3,w3a.x, ba.x))));
    h0.y = fmaf(x0,w0a.y, fmaf(x1,w1a.y, fmaf(x2,w2a.y, fmaf(x3,w3a.y, ba.y))));
    h0.z = fmaf(x0,w0a.z, fmaf(x1,w1a.z, fmaf(x2,w2a.z, fmaf(x3,w3a.z, ba.z))));
    h0.w = fmaf(x0,w0a.w, fmaf(x1,w1a.w, fmaf(x2,w2a.w, fmaf(x3,w3a.w, ba.w))));
    h1.x = fmaf(x0,w0b.x, fmaf(x1,w1b.x, fmaf(x2,w2b.x, fmaf(x3,w3b.x, bb.x))));
    h1.y = fmaf(x0,w0b.y, fmaf(x1,w1b.y, fmaf(x2,w2b.y, fmaf(x3,w3b.y, bb.y))));
    h1.z = fmaf(x0,w0b.z, fmaf(x1,w1b.z, fmaf(x2,w2b.z, fmaf(x3,w3b.z, bb.z))));
    h1.w = fmaf(x0,w0b.w, fmaf(x1,w1b.w, fmaf(x2,w2b.w, fmaf(x3,w3b.w, bb.w))));
    h0 = relu4(h0); h1 = relu4(h1);
    o0.x = 0.9f*(acc0[r].x + bpa.x + bna.x) + 0.1f*h0.x;
    o0.y = 0.9f*(acc0[r].y + bpa.y + bna.y) + 0.1f*h0.y;
    o0.z = 0.9f*(acc0[r].z + bpa.z + bna.z) + 0.1f*h0.z;
    o0.w = 0.9f*(acc0[r].w + bpa.w + bna.w) + 0.1f*h0.w;
    o1.x = 0.9f*(acc1[r].x + bpb.x + bnb.x) + 0.1f*h1.x;
    o1.y = 0.9f*(acc1[r].y + bpb.y + bnb.y) + 0.1f*h1.y;
    o1.z = 0.9f*(acc1[r].z + bpb.z + bnb.z) + 0.1f*h1.z;
    o1.w = 0.9f*(acc1[r].w + bpb.w + bnb.w) + 0.1f*h1.w;
    uint2 u;
    u.x = pack2(o0.x, o0.y); u.y = pack2(o0.z, o0.w);
    *(uint2*)(vmid + (size_t)row*64 + cg*2) = u;
    u.x = pack2(o1.x, o1.y); u.y = pack2(o1.z, o1.w);
    *(uint2*)(vmid + (size_t)row*64 + 32 + cg*2) = u;
  }
}

// fused clause update:
// c_h = relu(0.9*(mean_p(y_p) + mean_n(y_n) + c_h@B + blp + bln) + 0.1*relu(cemb))
// in-place on c_h (each block reads only its own A rows). ch/chout alias: no restrict.
__global__ __launch_bounds__(512) void k_gemm_c(const uint* ch, const float* __restrict__ B,
    const int* __restrict__ ipp, const int* __restrict__ epp,
    const int* __restrict__ ipn, const int* __restrict__ epn,
    const uint* __restrict__ Yp, const uint* __restrict__ Yn,
    const float* __restrict__ xc, const float* __restrict__ Wc, const float* __restrict__ bc,
    const float* __restrict__ blp, const float* __restrict__ bln,
    uint* chout){
  __shared__ float4 As4[4096];
  __shared__ float4 Bs4[4096];
  int t = threadIdx.x, m0 = blockIdx.x * 128;
  stageA_bf(ch, As4, m0, NCC, t);
  stageB(B, Bs4, t);
  __syncthreads();
  int cg = t & 15, rg = t >> 4;
  float4 acc0[4], acc1[4];
  ZERO4(acc0) ZERO4(acc1)
  kloop(As4, Bs4, rg, cg, acc0, acc1);
  __syncthreads();   // all B reads done before overwriting with result tile
  #pragma unroll
  for (int r = 0; r < 4; ++r){
    int lr = rg*4 + r;
    Bs4[lr*32 + (cg ^ (lr & 31))]        = acc0[r];
    Bs4[lr*32 + ((cg+16) ^ (lr & 31))]   = acc1[r];
  }
  __syncthreads();

  // phase 3: 4 threads per row, 32 cols each
  int lr = t >> 2, q = t & 3, row = m0 + lr;
  if (row >= NCC) return;
  float4 acc[8];
  #pragma unroll
  for (int m = 0; m < 8; ++m) acc[m] = make_float4(0.f,0.f,0.f,0.f);

  int s = row ? ipp[row-1] : 0, e = ipp[row];
  for (int j = s; j < e; ++j){
    const uint4* yr = (const uint4*)Yp + (size_t)epp[j]*16 + q*4;
    #pragma unroll
    for (int m = 0; m < 4; ++m){
      uint4 u = yr[m];
      acc[2*m].x   += bf2f(u.x & 0xFFFFu); acc[2*m].y   += bf2f(u.x >> 16);
      acc[2*m].z   += bf2f(u.y & 0xFFFFu); acc[2*m].w   += bf2f(u.y >> 16);
      acc[2*m+1].x += bf2f(u.z & 0xFFFFu); acc[2*m+1].y += bf2f(u.z >> 16);
      acc[2*m+1].z += bf2f(u.w & 0xFFFFu); acc[2*m+1].w += bf2f(u.w >> 16);
    }
  }
  float invp = 1.f / fmaxf((float)(e - s), 1.f);
  #pragma unroll
  for (int m = 0; m < 8; ++m){
    acc[m].x *= invp; acc[m].y *= invp; acc[m].z *= invp; acc[m].w *= invp;
  }
  s = row ? ipn[row-1] : 0; e = ipn[row];
  float invn = 1.f / fmaxf((float)(e - s), 1.f);
  for (int j = s; j < e; ++j){
    const uint4* yr = (const uint4*)Yn + (size_t)epn[j]*16 + q*4;
    #pragma unroll
    for (int m = 0; m < 4; ++m){
      uint4 u = yr[m];
      acc[2*m].x   = fmaf(bf2f(u.x & 0xFFFFu), invn, acc[2*m].x);
      acc[2*m].y   = fmaf(bf2f(u.x >> 16),     invn, acc[2*m].y);
      acc[2*m].z   = fmaf(bf2f(u.y & 0xFFFFu), invn, acc[2*m].z);
      acc[2*m].w   = fmaf(bf2f(u.y >> 16),     invn, acc[2*m].w);
      acc[2*m+1].x = fmaf(bf2f(u.z & 0xFFFFu), invn, acc[2*m+1].x);
      acc[2*m+1].y = fmaf(bf2f(u.z >> 16),     invn, acc[2*m+1].y);
      acc[2*m+1].z = fmaf(bf2f(u.w & 0xFFFFu), invn, acc[2*m+1].z);
      acc[2*m+1].w = fmaf(bf2f(u.w >> 16),     invn, acc[2*m+1].w);
    }
  }
  float xcv = xc[row];
  #pragma unroll
  for (int m = 0; m < 8; ++m){
    int c4 = q*8 + m;
    float4 res = Bs4[lr*32 + (c4 ^ (lr & 31))];
    float4 wc  = ((const float4*)Wc)[c4];
    float4 bcv = ((const float4*)bc)[c4];
    float4 bp  = ((const float4*)blp)[c4];
    float4 bn  = ((const float4*)bln)[c4];
    float4 h0;
    h0.x = fmaxf(fmaf(xcv, wc.x, bcv.x), 0.f);
    h0.y = fmaxf(fmaf(xcv, wc.y, bcv.y), 0.f);
    h0.z = fmaxf(fmaf(xcv, wc.z, bcv.z), 0.f);
    h0.w = fmaxf(fmaf(xcv, wc.w, bcv.w), 0.f);
    float4 o;
    o.x = fmaxf(0.9f*(acc[m].x + res.x + bp.x + bn.x) + 0.1f*h0.x, 0.f);
    o.y = fmaxf(0.9f*(acc[m].y + res.y + bp.y + bn.y) + 0.1f*h0.y, 0.f);
    o.z = fmaxf(0.9f*(acc[m].z + res.z + bp.z + bn.z) + 0.1f*h0.z, 0.f);
    o.w = fmaxf(0.9f*(acc[m].w + res.w + bp.w + bn.w) + 0.1f*h0.w, 0.f);
    uint2 u2; u2.x = pack2(o.x, o.y); u2.y = pack2(o.z, o.w);
    *(uint2*)(chout + (size_t)row*64 + c4*2) = u2;
  }
}

// v_h = relu(omb*vmid + beta*(vmid@B + bv) + v_h)   (in-place v_h)
__global__ __launch_bounds__(512) void k_gemm_f(const uint* __restrict__ Avm,
    const float* __restrict__ B, const float* __restrict__ bvv,
    float omb, float beta, float* vh, int M){
  __shared__ float4 As4[4096];
  __shared__ float4 Bs4[4096];
  int t = threadIdx.x, m0 = blockIdx.x * 128;
  stageA_bf(Avm, As4, m0, M, t);
  stageB(B, Bs4, t);
  __syncthreads();
  int cg = t & 15, rg = t >> 4;
  float4 acc0[4], acc1[4];
  ZERO4(acc0) ZERO4(acc1)
  kloop(As4, Bs4, rg, cg, acc0, acc1);
  float4 ba = ((const float4*)bvv)[cg], bb = ((const float4*)bvv)[cg+16];
  #pragma unroll
  for (int r = 0; r < 4; ++r){
    int lr = rg*4 + r, row = m0 + lr;
    if (row >= M) continue;
    float4 mid0 = As4[lr*32 + (cg ^ ((lr >> 3) & 15))];
    float4 mid1 = As4[lr*32 + ((cg+16) ^ ((lr >> 3) & 15))];
    float4 v0 = *(float4*)(vh + (size_t)row*HH + cg*4);
    float4 v1 = *(float4*)(vh + (size_t)row*HH + 64 + cg*4);
    float4 o0, o1;
    o0.x = fmaxf(omb*mid0.x + beta*(acc0[r].x + ba.x) + v0.x, 0.f);
    o0.y = fmaxf(omb*mid0.y + beta*(acc0[r].y + ba.y) + v0.y, 0.f);
    o0.z = fmaxf(omb*mid0.z + beta*(acc0[r].z + ba.z) + v0.z, 0.f);
    o0.w = fmaxf(omb*mid0.w + beta*(acc0[r].w + ba.w) + v0.w, 0.f);
    o1.x = fmaxf(omb*mid1.x + beta*(acc1[r].x + bb.x) + v1.x, 0.f);
    o1.y = fmaxf(omb*mid1.y + beta*(acc1[r].y + bb.y) + v1.y, 0.f);
    o1.z = fmaxf(omb*mid1.z + beta*(acc1[r].z + bb.z) + v1.z, 0.f);
    o1.w = fmaxf(omb*mid1.w + beta*(acc1[r].w + bb.w) + v1.w, 0.f);
    *(float4*)(vh + (size_t)row*HH + cg*4)      = o0;
    *(float4*)(vh + (size_t)row*HH + 64 + cg*4) = o1;
  }
}

// out[i] = dot(v_h[i,:], W_fin) + b_fin   (one wave per row)
__global__ void k_final(const float* __restrict__ vh, const float* __restrict__ wf,
                        const float* __restrict__ bf, float* __restrict__ out){
  int wid = (blockIdx.x * 256 + threadIdx.x) >> 6;
  if (wid >= NVV) return;
  int lane = threadIdx.x & 63;
  float2 a = *(const float2*)(vh + (size_t)wid*HH + lane*2);
  float2 w = *(const float2*)(wf + lane*2);
  float s = a.x*w.x + a.y*w.y;
  #pragma unroll
  for (int off = 32; off > 0; off >>= 1) s += __shfl_down(s, off);
  if (lane == 0) out[wid] = s + bf[0];
}

// ---------------- orchestration ----------------
extern "C" void kernel_launch(void* const* d_in, const int* in_sizes, int n_in,
                              void* d_out, int out_size, void* d_ws, size_t ws_size,
                              hipStream_t stream) {
  const float* xv  = (const float*)d_in[0];
  const float* xc  = (const float*)d_in[1];
  const int*   ep  = (const int*)d_in[2];
  const int*   en  = (const int*)d_in[3];
  const float* Wve = (const float*)d_in[4];
  const float* bve = (const float*)d_in[5];
  const float* Wce = (const float*)d_in[6];
  const float* bce = (const float*)d_in[7];
  const float* Wl_pos  = (const float*)d_in[8];
  const float* bl_pos  = (const float*)d_in[9];
  const float* Wr_pos  = (const float*)d_in[10];
  const float* Wl_neg  = (const float*)d_in[11];
  const float* bl_neg  = (const float*)d_in[12];
  const float* Wr_neg  = (const float*)d_in[13];
  const float* Wl_rpos = (const float*)d_in[14];
  const float* bl_rpos = (const float*)d_in[15];
  const float* Wr_rpos = (const float*)d_in[16];
  const float* Wl_rneg = (const float*)d_in[17];
  const float* bl_rneg = (const float*)d_in[18];
  const float* Wr_rneg = (const float*)d_in[19];
  const float* Wv  = (const float*)d_in[20];
  const float* bv  = (const float*)d_in[21];
  const float* Wf  = (const float*)d_in[22];
  const float* bf  = (const float*)d_in[23];
  float* out = (float*)d_out;

  size_t off = 0;
  auto alloc = [&](size_t bytes) -> void* {
    void* p = (char*)d_ws + off;
    off = (off + bytes + 255) & ~(size_t)255;
    return p;
  };
  uint*  c_h    = (uint*) alloc((size_t)NCC*64*sizeof(uint));   // bf16 NCxH   107.5 MB
  float* v_h    = (float*)alloc((size_t)NVV*HH*sizeof(float));  // f32  NVxH    51.2 MB
  uint*  U1     = (uint*) alloc((size_t)NVV*64*sizeof(uint));   // bf16 NVxH    25.6 MB
  uint*  U2     = (uint*) alloc((size_t)NVV*64*sizeof(uint));   // bf16 NVxH    25.6 MB
  uint*  vmid   = (uint*) alloc((size_t)NVV*64*sizeof(uint));   // bf16 NVxH    25.6 MB
  float* wsum_c = (float*)alloc((size_t)LL*HH*HH*sizeof(float));
  float* wsum_v = (float*)alloc((size_t)LL*HH*HH*sizeof(float));
  int* ipc_p = (int*)alloc((size_t)NCC*sizeof(int));
  int* ec_p  = (int*)alloc((size_t)EE*sizeof(int));
  int* ipc_n = (int*)alloc((size_t)NCC*sizeof(int));
  int* ec_n  = (int*)alloc((size_t)EE*sizeof(int));
  int* ipv_p = (int*)alloc((size_t)NVV*sizeof(int));
  int* ev_p  = (int*)alloc((size_t)EE*sizeof(int));
  int* ipv_n = (int*)alloc((size_t)NVV*sizeof(int));
  int* ev_n  = (int*)alloc((size_t)EE*sizeof(int));
  int* cnt   = (int*)alloc((size_t)NCC*sizeof(int));
  int* part  = (int*)alloc(4096);
  if (off > ws_size){
    k_sentinel<<<1, 64, 0, stream>>>(out, (float)(ws_size >> 20));
    return;
  }

  const int TB = 256;
  const int gE  = (EE + TB-1)/TB;
  const int gV  = (NVV*32 + TB-1)/TB;
  const int gC  = (NCC*32 + TB-1)/TB;
  const int gGv = (NVV + 127)/128;
  const int gGc = (NCC + 127)/128;
  const int gWd = (NVV*64 + TB-1)/TB;   // wave-per-row kernels

  auto build = [&](const int* dst, const int* pay, int nd, int* ip, int* eo){
    hipMemsetAsync(cnt, 0, (size_t)nd*sizeof(int), stream);
    k_counti<<<gE, TB, 0, stream>>>(dst, cnt, EE);
    int nb = (nd + 1023)/1024;
    k_scanb<<<nb, TB, 0, stream>>>(cnt, ip, part, nd);
    k_scanp<<<1, TB, 0, stream>>>(part, nb);
    k_scana<<<(nd + TB-1)/TB, TB, 0, stream>>>(ip, part, nd);
    k_fill<<<gE, TB, 0, stream>>>(dst, pay, ip, eo, EE);
  };
  build(ep + EE, ep,      NCC, ipc_p, ec_p);   // clause <- pos edges, payload = variable
  build(en + EE, en,      NCC, ipc_n, ec_n);
  build(ep,      ep + EE, NVV, ipv_p, ev_p);   // variable <- pos edges, payload = clause
  build(en,      en + EE, NVV, ipv_n, ev_n);

  k_addmat<<<(LL*HH*HH/4 + TB-1)/TB, TB, 0, stream>>>(Wr_pos,  Wr_neg,  wsum_c, LL*HH*HH/4);
  k_addmat<<<(LL*HH*HH/4 + TB-1)/TB, TB, 0, stream>>>(Wr_rpos, Wr_rneg, wsum_v, LL*HH*HH/4);

  k_embed_v<<<gV, TB, 0, stream>>>(xv, Wve, bve, v_h);
  k_embed_c<<<gC, TB, 0, stream>>>(xc, Wce, bce, c_h);

  for (int l = 0; l < LL; ++l){
    const size_t wo = (size_t)l*HH*HH;
    const size_t bo = (size_t)l*HH;
    double beta_d = log(0.5/(double)(l+1) + 1.0);

    // v-side aggregation from OLD c_h
    k_vgather<<<gWd, TB, 0, stream>>>(c_h, ipv_p, ev_p, ipv_n, ev_n, U1, U2);
    // vmid = 0.9*(agg_p@Wl_rpos + agg_n@Wl_rneg + v_h@wsum_v + biases) + 0.1*relu(vemb)
    k_gemm3<<<gGv, 512, 0, stream>>>(U1, Wl_rpos + wo, U2, Wl_rneg + wo,
                                     v_h, wsum_v + wo, xv, Wve, bve,
                                     bl_rpos + bo, bl_rneg + bo, vmid, NVV);
    // y_p, y_n from OLD v_h (reuses U1/U2)
    k_gemm_dual<<<gGv, 512, 0, stream>>>(v_h, Wl_pos + wo, Wl_neg + wo, U1, U2, NVV);
    // clause update, in-place c_h
    k_gemm_c<<<gGc, 512, 0, stream>>>(c_h, wsum_c + wo, ipc_p, ec_p, ipc_n, ec_n,
                                      U1, U2, xc, Wce, bce,
                                      bl_pos + bo, bl_neg + bo, c_h);
    // v_h = relu(omb*vmid + beta*(vmid@Wv + bv) + v_h), in-place v_h
    k_gemm_f<<<gGv, 512, 0, stream>>>(vmid, Wv + wo, bv + bo,
                                      (float)(1.0 - beta_d), (float)beta_d, v_h, NVV);
  }

  k_final<<<gWd, TB, 0, stream>>>(v_h, Wf, bf, out);
}

// Round 4
// 3774.291 us; speedup vs baseline: 2.1582x; 2.1582x over previous
//
#include <hip/hip_runtime.h>
#include <math.h>

#define NVV 100000
#define NCC 420000
#define EE  630000
#define HH  128
#define LL  8

typedef unsigned int uint;
typedef unsigned short ushort;
typedef __attribute__((ext_vector_type(8))) short bf16x8;
typedef __attribute__((ext_vector_type(4))) float f32x4;

#define MFMA16(a,b,c) __builtin_amdgcn_mfma_f32_16x16x32_bf16(a,b,c,0,0,0)
// swizzled ushort index within a [128 rows][128 cols-of-bf16] LDS tile
#define SW(r,k) (((r)<<7) + ((k) ^ (((r)&7)<<3)))

// ---------------- bf16 helpers (bit-level, RNE) ----------------
__device__ inline float bf2f(uint u){ return __uint_as_float(u << 16); }
__device__ inline uint  f2bf(float f){
  uint b = __float_as_uint(f);
  return (b + 0x7FFFu + ((b >> 16) & 1u)) >> 16;
}
__device__ inline uint pack2(float a, float b){ return f2bf(a) | (f2bf(b) << 16); }
__device__ inline float4 relu4(float4 v){
  v.x = fmaxf(v.x, 0.f); v.y = fmaxf(v.y, 0.f);
  v.z = fmaxf(v.z, 0.f); v.w = fmaxf(v.w, 0.f);
  return v;
}

__global__ void k_sentinel(float* out, float v){
  if (blockIdx.x == 0 && threadIdx.x == 0) out[0] = v;
}

// ---------------- embeddings ----------------
__device__ inline float4 vemb4(const float* __restrict__ xv, const float* __restrict__ W,
                               const float* __restrict__ b, int i, int h4){
  float x0 = xv[4*i+0], x1 = xv[4*i+1], x2 = xv[4*i+2], x3 = xv[4*i+3];
  float4 w0 = *(const float4*)(W + 0*HH + h4);
  float4 w1 = *(const float4*)(W + 1*HH + h4);
  float4 w2 = *(const float4*)(W + 2*HH + h4);
  float4 w3 = *(const float4*)(W + 3*HH + h4);
  float4 bb = *(const float4*)(b + h4);
  float4 r;
  r.x = fmaf(x0,w0.x, fmaf(x1,w1.x, fmaf(x2,w2.x, fmaf(x3,w3.x, bb.x))));
  r.y = fmaf(x0,w0.y, fmaf(x1,w1.y, fmaf(x2,w2.y, fmaf(x3,w3.y, bb.y))));
  r.z = fmaf(x0,w0.z, fmaf(x1,w1.z, fmaf(x2,w2.z, fmaf(x3,w3.z, bb.z))));
  r.w = fmaf(x0,w0.w, fmaf(x1,w1.w, fmaf(x2,w2.w, fmaf(x3,w3.w, bb.w))));
  return r;
}

__global__ void k_embed_v(const float* __restrict__ xv, const float* __restrict__ W,
                          const float* __restrict__ b, float* __restrict__ out){
  int tid = blockIdx.x * 256 + threadIdx.x;
  int i = tid >> 5;
  if (i >= NVV) return;
  int h4 = (tid & 31) << 2;
  *(float4*)(out + (size_t)i*HH + h4) = relu4(vemb4(xv, W, b, i, h4));
}

__global__ void k_embed_c(const float* __restrict__ xc, const float* __restrict__ W,
                          const float* __restrict__ b, uint* __restrict__ out){
  int tid = blockIdx.x * 256 + threadIdx.x;
  int i = tid >> 5;
  if (i >= NCC) return;
  int c2 = tid & 31;
  int h4 = c2 << 2;
  float x0 = xc[i];
  float4 w = *(const float4*)(W + h4);
  float4 bb = *(const float4*)(b + h4);
  float4 r;
  r.x = fmaxf(fmaf(x0, w.x, bb.x), 0.f);
  r.y = fmaxf(fmaf(x0, w.y, bb.y), 0.f);
  r.z = fmaxf(fmaf(x0, w.z, bb.z), 0.f);
  r.w = fmaxf(fmaf(x0, w.w, bb.w), 0.f);
  uint2 o; o.x = pack2(r.x, r.y); o.y = pack2(r.z, r.w);
  *(uint2*)(out + (size_t)i*64 + c2*2) = o;
}

// ---------------- weight prep: transpose + swizzle + hi/lo split ----------------
// wt layout: [mat 0..6][layer 0..7][hi/lo][16384 ushorts], element (n,k) at SW(n,k)
// mats: 0 Wl_pos, 1 Wl_neg, 2 Wl_rpos, 3 Wl_rneg, 4 Wv, 5 Wr_pos+Wr_neg, 6 Wr_rpos+Wr_rneg
__global__ void k_prep(const float* __restrict__ Wl_pos, const float* __restrict__ Wl_neg,
                       const float* __restrict__ Wl_rpos, const float* __restrict__ Wl_rneg,
                       const float* __restrict__ Wv, const float* __restrict__ Wr_pos,
                       const float* __restrict__ Wr_neg, const float* __restrict__ Wr_rpos,
                       const float* __restrict__ Wr_rneg, ushort* __restrict__ wt){
  int tid = blockIdx.x * 256 + threadIdx.x;   // 7*8*128*32 threads
  int n4 = tid & 31, k = (tid >> 5) & 127, l = (tid >> 12) & 7, m = tid >> 15;
  const float* s1; const float* s2 = nullptr;
  switch (m){
    case 0: s1 = Wl_pos;  break;
    case 1: s1 = Wl_neg;  break;
    case 2: s1 = Wl_rpos; break;
    case 3: s1 = Wl_rneg; break;
    case 4: s1 = Wv;      break;
    case 5: s1 = Wr_pos;  s2 = Wr_neg;  break;
    default: s1 = Wr_rpos; s2 = Wr_rneg; break;
  }
  size_t o = (size_t)l*16384 + (size_t)k*128 + n4*4;
  float4 w = *(const float4*)(s1 + o);
  if (s2){
    float4 w2 = *(const float4*)(s2 + o);
    w.x += w2.x; w.y += w2.y; w.z += w2.z; w.w += w2.w;
  }
  ushort* hi = wt + (size_t)((m*LL + l)*2    )*16384;
  ushort* lo = wt + (size_t)((m*LL + l)*2 + 1)*16384;
  float vv[4] = {w.x, w.y, w.z, w.w};
  #pragma unroll
  for (int e = 0; e < 4; ++e){
    int n = n4*4 + e;
    uint h = f2bf(vv[e]);
    float r = vv[e] - bf2f(h);
    hi[SW(n, k)] = (ushort)h;
    lo[SW(n, k)] = (ushort)f2bf(r);
  }
}

// ---------------- CSR build ----------------
__global__ void k_counti(const int* __restrict__ d, int* cnt, int n){
  int i = blockIdx.x * 256 + threadIdx.x;
  if (i < n) atomicAdd(&cnt[d[i]], 1);
}

#define SCAN256(ts, t) \
  for (int off = 1; off < 256; off <<= 1){ \
    int _a = (t >= off) ? ts[t - off] : 0; \
    __syncthreads(); \
    ts[t] += _a; \
    __syncthreads(); \
  }

__global__ void k_scanb(const int* __restrict__ in, int* __restrict__ out,
                        int* __restrict__ part, int n){
  __shared__ int ts[256];
  int b = blockIdx.x, t = threadIdx.x;
  int base = b*1024 + t*4;
  int v0 = (base+0 < n) ? in[base+0] : 0;
  int v1 = (base+1 < n) ? in[base+1] : 0;
  int v2 = (base+2 < n) ? in[base+2] : 0;
  int v3 = (base+3 < n) ? in[base+3] : 0;
  int s1 = v0, s2 = s1+v1, s3 = s2+v2, tsum = s3+v3;
  ts[t] = tsum; __syncthreads();
  SCAN256(ts, t)
  int excl = ts[t] - tsum;
  if (base+0 < n) out[base+0] = excl;
  if (base+1 < n) out[base+1] = excl + s1;
  if (base+2 < n) out[base+2] = excl + s2;
  if (base+3 < n) out[base+3] = excl + s3;
  if (t == 255) part[b] = ts[255];
}

__global__ void k_scanp(int* p, int nb){
  __shared__ int ts[256];
  __shared__ int carry;
  int t = threadIdx.x;
  if (t == 0) carry = 0;
  __syncthreads();
  for (int c = 0; c*256 < nb; ++c){
    int i = c*256 + t;
    int v = (i < nb) ? p[i] : 0;
    ts[t] = v; __syncthreads();
    SCAN256(ts, t)
    int excl = ts[t] - v + carry;
    if (i < nb) p[i] = excl;
    int tot = ts[255];
    __syncthreads();
    if (t == 0) carry += tot;
    __syncthreads();
  }
}

__global__ void k_scana(int* out, const int* __restrict__ part, int n){
  int i = blockIdx.x * 256 + threadIdx.x;
  if (i < n) out[i] += part[i >> 10];
}

__global__ void k_fill(const int* __restrict__ dst, const int* __restrict__ pay,
                       int* cur, int* __restrict__ eo, int n){
  int i = blockIdx.x * 256 + threadIdx.x;
  if (i >= n) return;
  int p = atomicAdd(&cur[dst[i]], 1);
  eo[p] = pay[i];
}

// ---------------- v-side CSR gather-mean (wave per variable row) ----------------
__global__ void k_vgather(const uint* __restrict__ ch,
                          const int* __restrict__ ipp, const int* __restrict__ epp,
                          const int* __restrict__ ipn, const int* __restrict__ epn,
                          uint* __restrict__ Up, uint* __restrict__ Un){
  int g = blockIdx.x * 256 + threadIdx.x;
  int v = g >> 6, lane = g & 63;
  if (v >= NVV) return;
  int s = v ? ipp[v-1] : 0, e = ipp[v];
  float a0 = 0.f, a1 = 0.f;
  for (int j = s; j < e; ++j){
    uint u = ch[(size_t)epp[j]*64 + lane];
    a0 += bf2f(u & 0xFFFFu); a1 += bf2f(u >> 16);
  }
  float inv = 1.f / fmaxf((float)(e - s), 1.f);
  Up[(size_t)v*64 + lane] = pack2(a0*inv, a1*inv);
  s = v ? ipn[v-1] : 0; e = ipn[v];
  a0 = 0.f; a1 = 0.f;
  for (int j = s; j < e; ++j){
    uint u = ch[(size_t)epn[j]*64 + lane];
    a0 += bf2f(u & 0xFFFFu); a1 += bf2f(u >> 16);
  }
  inv = 1.f / fmaxf((float)(e - s), 1.f);
  Un[(size_t)v*64 + lane] = pack2(a0*inv, a1*inv);
}

// ---------------- MFMA GEMM building blocks (512 threads, 128x128 tile) ----------------
// LDS: As = lds[0:16384] (swizzled bf16 A tile), Bs = lds[16384:32768] (swizzled bf16 B^T)
__device__ inline void stA_bf16(const uint4* __restrict__ A, ushort* As, int m0, int M, int t){
  #pragma unroll
  for (int j = 0; j < 4; ++j){            // 128 rows x 16 uint4
    int idx = j*512 + t, r = idx >> 4, c = idx & 15;
    uint4 v = make_uint4(0,0,0,0);
    if (m0 + r < M) v = A[(size_t)(m0 + r)*16 + c];
    *(uint4*)(As + SW(r, c*8)) = v;
  }
}

__device__ inline void stA_f32(const float* __restrict__ A, ushort* As, int m0, int M, int t){
  const float4* A4 = (const float4*)A;
  #pragma unroll
  for (int j = 0; j < 8; ++j){            // 128 rows x 32 float4
    int idx = j*512 + t, r = idx >> 5, c = idx & 31;
    float4 v = make_float4(0.f,0.f,0.f,0.f);
    if (m0 + r < M) v = A4[(size_t)(m0 + r)*32 + c];
    uint2 u; u.x = pack2(v.x, v.y); u.y = pack2(v.z, v.w);
    *(uint2*)(As + SW(r, c*4)) = u;
  }
}

__device__ inline void stB(const uint4* __restrict__ Bt, ushort* Bs, int t){
  #pragma unroll
  for (int j = 0; j < 4; ++j) ((uint4*)Bs)[j*512 + t] = Bt[j*512 + t];
}

// wave tile: rows wr*32..+31 (m_rep 2), cols wc*64..+63 (n_rep 4)
__device__ inline void kloop(const ushort* As, const ushort* Bs, int wr, int wc,
                             int l15, int g, f32x4 acc[2][4]){
  #pragma unroll
  for (int kk = 0; kk < 4; ++kk){
    int kb = kk*32 + g*8;
    bf16x8 a0 = *(const bf16x8*)(As + SW(wr*32 + l15,      kb));
    bf16x8 a1 = *(const bf16x8*)(As + SW(wr*32 + 16 + l15, kb));
    #pragma unroll
    for (int ni = 0; ni < 4; ++ni){
      int n = wc*64 + ni*16 + l15;
      bf16x8 b = *(const bf16x8*)(Bs + SW(n, kb));
      acc[0][ni] = MFMA16(a0, b, acc[0][ni]);
      acc[1][ni] = MFMA16(a1, b, acc[1][ni]);
    }
  }
}

// acc -> LDS f32 [128][128], plain layout
__device__ inline void accStoreF(float* ldsF, f32x4 acc[2][4], int wr, int wc, int l15, int g){
  #pragma unroll
  for (int mi = 0; mi < 2; ++mi)
    #pragma unroll
    for (int ni = 0; ni < 4; ++ni)
      #pragma unroll
      for (int j = 0; j < 4; ++j)
        ldsF[(wr*32 + mi*16 + g*4 + j)*128 + wc*64 + ni*16 + l15] = acc[mi][ni][j];
}

// acc -> LDS f32, float4-group XOR swizzled (for row-wise readers)
__device__ inline void accStoreFsw(float* ldsF, f32x4 acc[2][4], int wr, int wc, int l15, int g){
  #pragma unroll
  for (int mi = 0; mi < 2; ++mi)
    #pragma unroll
    for (int ni = 0; ni < 4; ++ni)
      #pragma unroll
      for (int j = 0; j < 4; ++j){
        int r = wr*32 + mi*16 + g*4 + j;
        int c = wc*64 + ni*16 + l15;
        ldsF[r*128 + (((c >> 2) ^ (r & 31)) << 2) + (c & 3)] = acc[mi][ni][j];
      }
}

// acc -> LDS bf16 [128][128] at dst
__device__ inline void accStoreBf(ushort* dst, f32x4 acc[2][4], int wr, int wc, int l15, int g){
  #pragma unroll
  for (int mi = 0; mi < 2; ++mi)
    #pragma unroll
    for (int ni = 0; ni < 4; ++ni)
      #pragma unroll
      for (int j = 0; j < 4; ++j)
        dst[(wr*32 + mi*16 + g*4 + j)*128 + wc*64 + ni*16 + l15] =
            (ushort)f2bf(acc[mi][ni][j]);
}

#define MMHEAD \
  __shared__ ushort lds[32768]; \
  ushort* As = lds; ushort* Bs = lds + 16384; \
  int t = threadIdx.x, m0 = blockIdx.x * 128; \
  int w = t >> 6, l = t & 63, wr = w >> 1, wc = w & 1, l15 = l & 15, g = l >> 4; \
  const f32x4 zz = {0.f, 0.f, 0.f, 0.f};

// ---- Up = A@Bp, Un = A@Bn  (A = v_h f32; bf16 outputs) ----
__global__ __launch_bounds__(512) void k_mm_dual(const float* __restrict__ A,
    const uint4* __restrict__ Bph, const uint4* __restrict__ Bpl,
    const uint4* __restrict__ Bnh, const uint4* __restrict__ Bnl,
    uint4* __restrict__ Up, uint4* __restrict__ Un, int M){
  MMHEAD
  f32x4 accP[2][4], accN[2][4];
  #pragma unroll
  for (int mi = 0; mi < 2; ++mi)
    #pragma unroll
    for (int ni = 0; ni < 4; ++ni){ accP[mi][ni] = zz; accN[mi][ni] = zz; }
  stA_f32(A, As, m0, M, t);
  stB(Bph, Bs, t); __syncthreads();
  kloop(As, Bs, wr, wc, l15, g, accP); __syncthreads();
  stB(Bpl, Bs, t); __syncthreads();
  kloop(As, Bs, wr, wc, l15, g, accP); __syncthreads();
  stB(Bnh, Bs, t); __syncthreads();
  kloop(As, Bs, wr, wc, l15, g, accN); __syncthreads();
  stB(Bnl, Bs, t); __syncthreads();
  kloop(As, Bs, wr, wc, l15, g, accN); __syncthreads();
  accStoreBf(lds,         accP, wr, wc, l15, g);
  accStoreBf(lds + 16384, accN, wr, wc, l15, g);
  __syncthreads();
  #pragma unroll
  for (int j = 0; j < 4; ++j){            // 2048 uint4 per matrix
    int idx = j*512 + t, r = idx >> 4, c = idx & 15;
    if (m0 + r < M){
      Up[(size_t)(m0 + r)*16 + c] = ((const uint4*)lds)[idx];
      Un[(size_t)(m0 + r)*16 + c] = ((const uint4*)(lds + 16384))[idx];
    }
  }
}

// ---- vmid = 0.9*(Ap@Bp + An@Bn + Af@Bf + blp + bln) + 0.1*relu(vemb)  (bf16 out) ----
__global__ __launch_bounds__(512) void k_mm3(const uint4* __restrict__ Ap,
    const uint4* __restrict__ An, const float* __restrict__ Af,
    const uint4* __restrict__ Bph, const uint4* __restrict__ Bpl,
    const uint4* __restrict__ Bnh, const uint4* __restrict__ Bnl,
    const uint4* __restrict__ Bfh, const uint4* __restrict__ Bfl,
    const float* __restrict__ xv, const float* __restrict__ Wve, const float* __restrict__ bve,
    const float* __restrict__ blp, const float* __restrict__ bln,
    uint2* __restrict__ vmid, int M){
  MMHEAD
  f32x4 acc[2][4];
  #pragma unroll
  for (int mi = 0; mi < 2; ++mi)
    #pragma unroll
    for (int ni = 0; ni < 4; ++ni) acc[mi][ni] = zz;

  stA_bf16(Ap, As, m0, M, t); stB(Bph, Bs, t); __syncthreads();
  kloop(As, Bs, wr, wc, l15, g, acc); __syncthreads();
  stB(Bpl, Bs, t); __syncthreads();
  kloop(As, Bs, wr, wc, l15, g, acc); __syncthreads();

  stA_bf16(An, As, m0, M, t); stB(Bnh, Bs, t); __syncthreads();
  kloop(As, Bs, wr, wc, l15, g, acc); __syncthreads();
  stB(Bnl, Bs, t); __syncthreads();
  kloop(As, Bs, wr, wc, l15, g, acc); __syncthreads();

  stA_f32(Af, As, m0, M, t); stB(Bfh, Bs, t); __syncthreads();
  kloop(As, Bs, wr, wc, l15, g, acc); __syncthreads();
  stB(Bfl, Bs, t); __syncthreads();
  kloop(As, Bs, wr, wc, l15, g, acc); __syncthreads();

  float* ldsF = (float*)lds;
  accStoreF(ldsF, acc, wr, wc, l15, g);
  __syncthreads();
  #pragma unroll
  for (int j = 0; j < 8; ++j){            // 128 rows x 32 float4
    int idx = j*512 + t, r = idx >> 5, c4 = idx & 31;
    int row = m0 + r;
    if (row >= M) continue;
    float4 a4 = ((const float4*)ldsF)[r*32 + c4];
    float4 bp = ((const float4*)blp)[c4];
    float4 bn = ((const float4*)bln)[c4];
    float4 w0 = ((const float4*)Wve)[0*32 + c4];
    float4 w1 = ((const float4*)Wve)[1*32 + c4];
    float4 w2 = ((const float4*)Wve)[2*32 + c4];
    float4 w3 = ((const float4*)Wve)[3*32 + c4];
    float4 bb = ((const float4*)bve)[c4];
    float4 xx = *(const float4*)(xv + (size_t)row*4);
    float4 h;
    h.x = fmaf(xx.x,w0.x, fmaf(xx.y,w1.x, fmaf(xx.z,w2.x, fmaf(xx.w,w3.x, bb.x))));
    h.y = fmaf(xx.x,w0.y, fmaf(xx.y,w1.y, fmaf(xx.z,w2.y, fmaf(xx.w,w3.y, bb.y))));
    h.z = fmaf(xx.x,w0.z, fmaf(xx.y,w1.z, fmaf(xx.z,w2.z, fmaf(xx.w,w3.z, bb.z))));
    h.w = fmaf(xx.x,w0.w, fmaf(xx.y,w1.w, fmaf(xx.z,w2.w, fmaf(xx.w,w3.w, bb.w))));
    h = relu4(h);
    float4 o;
    o.x = 0.9f*(a4.x + bp.x + bn.x) + 0.1f*h.x;
    o.y = 0.9f*(a4.y + bp.y + bn.y) + 0.1f*h.y;
    o.z = 0.9f*(a4.z + bp.z + bn.z) + 0.1f*h.z;
    o.w = 0.9f*(a4.w + bp.w + bn.w) + 0.1f*h.w;
    uint2 u; u.x = pack2(o.x, o.y); u.y = pack2(o.z, o.w);
    vmid[(size_t)row*32 + c4] = u;
  }
}

// ---- v_h = relu(omb*vmid + beta*(vmid@Wv + bv) + v_h)  (f32 in-place) ----
__global__ __launch_bounds__(512) void k_mm_f(const uint4* __restrict__ Avm,
    const uint4* __restrict__ Bh, const uint4* __restrict__ Bl,
    const uint2* __restrict__ vmid, const float* __restrict__ bvv,
    float omb, float beta, float* vh, int M){
  MMHEAD
  f32x4 acc[2][4];
  #pragma unroll
  for (int mi = 0; mi < 2; ++mi)
    #pragma unroll
    for (int ni = 0; ni < 4; ++ni) acc[mi][ni] = zz;
  stA_bf16(Avm, As, m0, M, t); stB(Bh, Bs, t); __syncthreads();
  kloop(As, Bs, wr, wc, l15, g, acc); __syncthreads();
  stB(Bl, Bs, t); __syncthreads();
  kloop(As, Bs, wr, wc, l15, g, acc); __syncthreads();
  float* ldsF = (float*)lds;
  accStoreF(ldsF, acc, wr, wc, l15, g);
  __syncthreads();
  #pragma unroll
  for (int j = 0; j < 8; ++j){
    int idx = j*512 + t, r = idx >> 5, c4 = idx & 31;
    int row = m0 + r;
    if (row >= M) continue;
    float4 a4 = ((const float4*)ldsF)[r*32 + c4];
    uint2 um = vmid[(size_t)row*32 + c4];
    float4 bb = ((const float4*)bvv)[c4];
    float4 vo = *(const float4*)(vh + (size_t)row*HH + c4*4);
    float m0f = bf2f(um.x & 0xFFFFu), m1f = bf2f(um.x >> 16);
    float m2f = bf2f(um.y & 0xFFFFu), m3f = bf2f(um.y >> 16);
    float4 o;
    o.x = fmaxf(omb*m0f + beta*(a4.x + bb.x) + vo.x, 0.f);
    o.y = fmaxf(omb*m1f + beta*(a4.y + bb.y) + vo.y, 0.f);
    o.z = fmaxf(omb*m2f + beta*(a4.z + bb.z) + vo.z, 0.f);
    o.w = fmaxf(omb*m3f + beta*(a4.w + bb.w) + vo.w, 0.f);
    *(float4*)(vh + (size_t)row*HH + c4*4) = o;
  }
}

// ---- clause update (in-place c_h):
// c_h = relu(0.9*(mean_p(Yp) + mean_n(Yn) + c_h@wsum_c + blp + bln) + 0.1*relu(cemb)) ----
__global__ __launch_bounds__(512) void k_mm_c(const uint4* ch,
    const uint4* __restrict__ Bh, const uint4* __restrict__ Bl,
    const int* __restrict__ ipp, const int* __restrict__ epp,
    const int* __restrict__ ipn, const int* __restrict__ epn,
    const uint4* __restrict__ Yp, const uint4* __restrict__ Yn,
    const float* __restrict__ xc, const float* __restrict__ Wc, const float* __restrict__ bc,
    const float* __restrict__ blp, const float* __restrict__ bln,
    uint2* chout){
  MMHEAD
  f32x4 acc[2][4];
  #pragma unroll
  for (int mi = 0; mi < 2; ++mi)
    #pragma unroll
    for (int ni = 0; ni < 4; ++ni) acc[mi][ni] = zz;
  stA_bf16(ch, As, m0, NCC, t); stB(Bh, Bs, t); __syncthreads();
  kloop(As, Bs, wr, wc, l15, g, acc); __syncthreads();
  stB(Bl, Bs, t); __syncthreads();
  kloop(As, Bs, wr, wc, l15, g, acc); __syncthreads();
  float* ldsF = (float*)lds;
  accStoreFsw(ldsF, acc, wr, wc, l15, g);
  __syncthreads();

  // phase 3: 4 threads per row, 32 cols each (col base q*32)
  int r = t >> 2, q = t & 3, row = m0 + r;
  if (row >= NCC) return;
  float4 ga[8];
  #pragma unroll
  for (int m = 0; m < 8; ++m) ga[m] = make_float4(0.f,0.f,0.f,0.f);
  int s = row ? ipp[row-1] : 0, e = ipp[row];
  for (int j = s; j < e; ++j){
    const uint4* yr = Yp + (size_t)epp[j]*16 + q*4;
    #pragma unroll
    for (int m = 0; m < 4; ++m){
      uint4 u = yr[m];
      ga[2*m].x   += bf2f(u.x & 0xFFFFu); ga[2*m].y   += bf2f(u.x >> 16);
      ga[2*m].z   += bf2f(u.y & 0xFFFFu); ga[2*m].w   += bf2f(u.y >> 16);
      ga[2*m+1].x += bf2f(u.z & 0xFFFFu); ga[2*m+1].y += bf2f(u.z >> 16);
      ga[2*m+1].z += bf2f(u.w & 0xFFFFu); ga[2*m+1].w += bf2f(u.w >> 16);
    }
  }
  float invp = 1.f / fmaxf((float)(e - s), 1.f);
  #pragma unroll
  for (int m = 0; m < 8; ++m){
    ga[m].x *= invp; ga[m].y *= invp; ga[m].z *= invp; ga[m].w *= invp;
  }
  s = row ? ipn[row-1] : 0; e = ipn[row];
  float invn = 1.f / fmaxf((float)(e - s), 1.f);
  for (int j = s; j < e; ++j){
    const uint4* yr = Yn + (size_t)epn[j]*16 + q*4;
    #pragma unroll
    for (int m = 0; m < 4; ++m){
      uint4 u = yr[m];
      ga[2*m].x   = fmaf(bf2f(u.x & 0xFFFFu), invn, ga[2*m].x);
      ga[2*m].y   = fmaf(bf2f(u.x >> 16),     invn, ga[2*m].y);
      ga[2*m].z   = fmaf(bf2f(u.y & 0xFFFFu), invn, ga[2*m].z);
      ga[2*m].w   = fmaf(bf2f(u.y >> 16),     invn, ga[2*m].w);
      ga[2*m+1].x = fmaf(bf2f(u.z & 0xFFFFu), invn, ga[2*m+1].x);
      ga[2*m+1].y = fmaf(bf2f(u.z >> 16),     invn, ga[2*m+1].y);
      ga[2*m+1].z = fmaf(bf2f(u.w & 0xFFFFu), invn, ga[2*m+1].z);
      ga[2*m+1].w = fmaf(bf2f(u.w >> 16),     invn, ga[2*m+1].w);
    }
  }
  float xcv = xc[row];
  #pragma unroll
  for (int m = 0; m < 8; ++m){
    int gi = q*8 + m;
    float4 res = ((const float4*)ldsF)[r*32 + (gi ^ (r & 31))];
    float4 wc  = ((const float4*)Wc)[gi];
    float4 bcv = ((const float4*)bc)[gi];
    float4 bp  = ((const float4*)blp)[gi];
    float4 bn  = ((const float4*)bln)[gi];
    float4 h;
    h.x = fmaxf(fmaf(xcv, wc.x, bcv.x), 0.f);
    h.y = fmaxf(fmaf(xcv, wc.y, bcv.y), 0.f);
    h.z = fmaxf(fmaf(xcv, wc.z, bcv.z), 0.f);
    h.w = fmaxf(fmaf(xcv, wc.w, bcv.w), 0.f);
    float4 o;
    o.x = fmaxf(0.9f*(ga[m].x + res.x + bp.x + bn.x) + 0.1f*h.x, 0.f);
    o.y = fmaxf(0.9f*(ga[m].y + res.y + bp.y + bn.y) + 0.1f*h.y, 0.f);
    o.z = fmaxf(0.9f*(ga[m].z + res.z + bp.z + bn.z) + 0.1f*h.z, 0.f);
    o.w = fmaxf(0.9f*(ga[m].w + res.w + bp.w + bn.w) + 0.1f*h.w, 0.f);
    uint2 u2; u2.x = pack2(o.x, o.y); u2.y = pack2(o.z, o.w);
    chout[(size_t)row*32 + gi] = u2;
  }
}

// out[i] = dot(v_h[i,:], W_fin) + b_fin   (one wave per row)
__global__ void k_final(const float* __restrict__ vh, const float* __restrict__ wf,
                        const float* __restrict__ bf, float* __restrict__ out){
  int wid = (blockIdx.x * 256 + threadIdx.x) >> 6;
  if (wid >= NVV) return;
  int lane = threadIdx.x & 63;
  float2 a = *(const float2*)(vh + (size_t)wid*HH + lane*2);
  float2 w = *(const float2*)(wf + lane*2);
  float s = a.x*w.x + a.y*w.y;
  #pragma unroll
  for (int off = 32; off > 0; off >>= 1) s += __shfl_down(s, off);
  if (lane == 0) out[wid] = s + bf[0];
}

// ---------------- orchestration ----------------
extern "C" void kernel_launch(void* const* d_in, const int* in_sizes, int n_in,
                              void* d_out, int out_size, void* d_ws, size_t ws_size,
                              hipStream_t stream) {
  const float* xv  = (const float*)d_in[0];
  const float* xc  = (const float*)d_in[1];
  const int*   ep  = (const int*)d_in[2];
  const int*   en  = (const int*)d_in[3];
  const float* Wve = (const float*)d_in[4];
  const float* bve = (const float*)d_in[5];
  const float* Wce = (const float*)d_in[6];
  const float* bce = (const float*)d_in[7];
  const float* Wl_pos  = (const float*)d_in[8];
  const float* bl_pos  = (const float*)d_in[9];
  const float* Wr_pos  = (const float*)d_in[10];
  const float* Wl_neg  = (const float*)d_in[11];
  const float* bl_neg  = (const float*)d_in[12];
  const float* Wr_neg  = (const float*)d_in[13];
  const float* Wl_rpos = (const float*)d_in[14];
  const float* bl_rpos = (const float*)d_in[15];
  const float* Wr_rpos = (const float*)d_in[16];
  const float* Wl_rneg = (const float*)d_in[17];
  const float* bl_rneg = (const float*)d_in[18];
  const float* Wr_rneg = (const float*)d_in[19];
  const float* Wv  = (const float*)d_in[20];
  const float* bv  = (const float*)d_in[21];
  const float* Wf  = (const float*)d_in[22];
  const float* bf  = (const float*)d_in[23];
  float* out = (float*)d_out;

  size_t off = 0;
  auto alloc = [&](size_t bytes) -> void* {
    void* p = (char*)d_ws + off;
    off = (off + bytes + 255) & ~(size_t)255;
    return p;
  };
  uint*   c_h  = (uint*)  alloc((size_t)NCC*64*sizeof(uint));   // bf16 NCxH
  float*  v_h  = (float*) alloc((size_t)NVV*HH*sizeof(float));  // f32  NVxH
  uint*   U1   = (uint*)  alloc((size_t)NVV*64*sizeof(uint));   // bf16 NVxH
  uint*   U2   = (uint*)  alloc((size_t)NVV*64*sizeof(uint));   // bf16 NVxH
  uint*   vmid = (uint*)  alloc((size_t)NVV*64*sizeof(uint));   // bf16 NVxH
  ushort* wt   = (ushort*)alloc((size_t)7*LL*2*16384*sizeof(ushort)); // weight images
  int* ipc_p = (int*)alloc((size_t)NCC*sizeof(int));
  int* ec_p  = (int*)alloc((size_t)EE*sizeof(int));
  int* ipc_n = (int*)alloc((size_t)NCC*sizeof(int));
  int* ec_n  = (int*)alloc((size_t)EE*sizeof(int));
  int* ipv_p = (int*)alloc((size_t)NVV*sizeof(int));
  int* ev_p  = (int*)alloc((size_t)EE*sizeof(int));
  int* ipv_n = (int*)alloc((size_t)NVV*sizeof(int));
  int* ev_n  = (int*)alloc((size_t)EE*sizeof(int));
  int* cnt   = (int*)alloc((size_t)NCC*sizeof(int));
  int* part  = (int*)alloc(4096);
  if (off > ws_size){
    k_sentinel<<<1, 64, 0, stream>>>(out, (float)(ws_size >> 20));
    return;
  }

  const int TB = 256;
  const int gE  = (EE + TB-1)/TB;
  const int gV  = (NVV*32 + TB-1)/TB;
  const int gC  = (NCC*32 + TB-1)/TB;
  const int gGv = (NVV + 127)/128;   // 782
  const int gGc = (NCC + 127)/128;   // 3282
  const int gWd = (NVV*64 + TB-1)/TB;

  // weight pointer: mat m, layer l, half h(0=hi,1=lo)
  auto wp = [&](int m, int l, int h) -> const uint4* {
    return (const uint4*)(wt + (size_t)((m*LL + l)*2 + h)*16384);
  };

  auto build = [&](const int* dst, const int* pay, int nd, int* ip, int* eo){
    hipMemsetAsync(cnt, 0, (size_t)nd*sizeof(int), stream);
    k_counti<<<gE, TB, 0, stream>>>(dst, cnt, EE);
    int nb = (nd + 1023)/1024;
    k_scanb<<<nb, TB, 0, stream>>>(cnt, ip, part, nd);
    k_scanp<<<1, TB, 0, stream>>>(part, nb);
    k_scana<<<(nd + TB-1)/TB, TB, 0, stream>>>(ip, part, nd);
    k_fill<<<gE, TB, 0, stream>>>(dst, pay, ip, eo, EE);
  };
  build(ep + EE, ep,      NCC, ipc_p, ec_p);
  build(en + EE, en,      NCC, ipc_n, ec_n);
  build(ep,      ep + EE, NVV, ipv_p, ev_p);
  build(en,      en + EE, NVV, ipv_n, ev_n);

  k_prep<<<(7*LL*128*32)/TB, TB, 0, stream>>>(Wl_pos, Wl_neg, Wl_rpos, Wl_rneg, Wv,
                                              Wr_pos, Wr_neg, Wr_rpos, Wr_rneg, wt);

  k_embed_v<<<gV, TB, 0, stream>>>(xv, Wve, bve, v_h);
  k_embed_c<<<gC, TB, 0, stream>>>(xc, Wce, bce, c_h);

  for (int l = 0; l < LL; ++l){
    const size_t bo = (size_t)l*HH;
    double beta_d = log(0.5/(double)(l+1) + 1.0);

    // v-side aggregation from OLD c_h
    k_vgather<<<gWd, TB, 0, stream>>>(c_h, ipv_p, ev_p, ipv_n, ev_n, U1, U2);
    // vmid
    k_mm3<<<gGv, 512, 0, stream>>>((const uint4*)U1, (const uint4*)U2, v_h,
                                   wp(2,l,0), wp(2,l,1), wp(3,l,0), wp(3,l,1),
                                   wp(6,l,0), wp(6,l,1),
                                   xv, Wve, bve, bl_rpos + bo, bl_rneg + bo,
                                   (uint2*)vmid, NVV);
    // y_p, y_n from OLD v_h (reuse U1/U2)
    k_mm_dual<<<gGv, 512, 0, stream>>>(v_h, wp(0,l,0), wp(0,l,1), wp(1,l,0), wp(1,l,1),
                                       (uint4*)U1, (uint4*)U2, NVV);
    // clause update, in-place c_h
    k_mm_c<<<gGc, 512, 0, stream>>>((const uint4*)c_h, wp(5,l,0), wp(5,l,1),
                                    ipc_p, ec_p, ipc_n, ec_n,
                                    (const uint4*)U1, (const uint4*)U2,
                                    xc, Wce, bce, bl_pos + bo, bl_neg + bo,
                                    (uint2*)c_h);
    // v_h update, in-place
    k_mm_f<<<gGv, 512, 0, stream>>>((const uint4*)vmid, wp(4,l,0), wp(4,l,1),
                                    (const uint2*)vmid, bv + bo,
                                    (float)(1.0 - beta_d), (float)beta_d, v_h, NVV);
  }

  k_final<<<gWd, TB, 0, stream>>>(v_h, Wf, bf, out);
}